// Round 1
// baseline (338.650 us; speedup 1.0000x reference)
//
#include <hip/hip_runtime.h>

typedef short bf16x8 __attribute__((ext_vector_type(8)));
typedef float f32x4 __attribute__((ext_vector_type(4)));

#define DI __device__ __forceinline__

static DI unsigned short f2bf(float f) {
  union { float f; unsigned u; } v; v.f = f;
  unsigned r = v.u + 0x7FFFu + ((v.u >> 16) & 1u);  // RNE
  return (unsigned short)(r >> 16);
}

// ---------------------------------------------------------------------------
// Weight prep: cast+transpose to bf16 [N][K] (n-major rows) so GEMM B-tiles
// stage as contiguous 16B rows and B-fragments are ds_read_b128-friendly.
// ---------------------------------------------------------------------------
__global__ __launch_bounds__(256) void k_cast_weights(
    const float* __restrict__ Wq, const float* __restrict__ Wk,
    const float* __restrict__ Wv, const float* __restrict__ Wg,
    const float* __restrict__ Wo,
    unsigned short* __restrict__ Wt_qkvg, unsigned short* __restrict__ Wt_o) {
  int t = blockIdx.x * 256 + threadIdx.x;
  if (t < 262144) {
    int n = t & 1023, kk = t >> 10;
    const float* W = (n < 256) ? Wq : (n < 512) ? Wk : (n < 768) ? Wv : Wg;
    Wt_qkvg[(size_t)n * 256 + kk] = f2bf(W[kk * 256 + (n & 255)]);
  } else if (t < 262144 + 65536) {
    int u = t - 262144;
    int n = u & 255, kk = u >> 8;
    Wt_o[n * 256 + kk] = f2bf(Wo[kk * 256 + n]);
  }
}

// ---------------------------------------------------------------------------
// rmsnorm(m) -> bf16. One wave per 256-elem row, float4 per lane.
// ---------------------------------------------------------------------------
__global__ __launch_bounds__(256) void k_rmsnorm_m(
    const float* __restrict__ m, const float* __restrict__ w,
    unsigned short* __restrict__ m_norm) {
  int wave = threadIdx.x >> 6, lane = threadIdx.x & 63;
  int row = blockIdx.x * 4 + wave;
  const float4 x = *(const float4*)(m + (size_t)row * 256 + lane * 4);
  float ss = x.x * x.x + x.y * x.y + x.z * x.z + x.w * x.w;
#pragma unroll
  for (int mk = 1; mk < 64; mk <<= 1) ss += __shfl_xor(ss, mk, 64);
  float rms = rsqrtf(ss * (1.0f / 256.0f) + 1e-5f);
  const float4 wv = *(const float4*)(w + lane * 4);
  ushort4 o;
  o.x = f2bf(x.x * rms * wv.x);
  o.y = f2bf(x.y * rms * wv.y);
  o.z = f2bf(x.z * rms * wv.z);
  o.w = f2bf(x.w * rms * wv.w);
  *(ushort4*)(m_norm + (size_t)row * 256 + lane * 4) = o;
}

// ---------------------------------------------------------------------------
// Pair bias: bias[h][i][j] = rmsnorm(z[i,j,:]) . (w_norm_z*Wz[:,h]) + mask.
// One wave per z-row (128 f32, float2/lane). Memory-bound on z (134 MB).
// Mask folded here so attention only adds one fp32 bias.
// ---------------------------------------------------------------------------
__global__ __launch_bounds__(256) void k_pair_bias(
    const float* __restrict__ z, const float* __restrict__ z_mask,
    const float* __restrict__ w_norm_z, const float* __restrict__ Wz,
    float* __restrict__ bias) {
  int wave = threadIdx.x >> 6, lane = threadIdx.x & 63;
  int row = blockIdx.x * 4 + wave;                 // 0..262143
  const float2 x = *(const float2*)(z + (size_t)row * 128 + lane * 2);
  float ss = x.x * x.x + x.y * x.y;
#pragma unroll
  for (int mk = 1; mk < 64; mk <<= 1) ss += __shfl_xor(ss, mk, 64);
  float rms = rsqrtf(ss * (1.0f / 128.0f) + 1e-5f);
  // per-lane weight slice (coalesced 64B from L1-resident 4KB Wz)
  float wn0 = w_norm_z[lane * 2], wn1 = w_norm_z[lane * 2 + 1];
  float4 wz0 = *(const float4*)(Wz + lane * 16);       // row 2l, h0..3
  float4 wz1 = *(const float4*)(Wz + lane * 16 + 4);   // row 2l, h4..7
  float4 wz2 = *(const float4*)(Wz + lane * 16 + 8);   // row 2l+1, h0..3
  float4 wz3 = *(const float4*)(Wz + lane * 16 + 12);  // row 2l+1, h4..7
  float c0 = x.x * wn0, c1 = x.y * wn1;
  float p[8];
  p[0] = c0 * wz0.x + c1 * wz2.x;
  p[1] = c0 * wz0.y + c1 * wz2.y;
  p[2] = c0 * wz0.z + c1 * wz2.z;
  p[3] = c0 * wz0.w + c1 * wz2.w;
  p[4] = c0 * wz1.x + c1 * wz3.x;
  p[5] = c0 * wz1.y + c1 * wz3.y;
  p[6] = c0 * wz1.z + c1 * wz3.z;
  p[7] = c0 * wz1.w + c1 * wz3.w;
#pragma unroll
  for (int h = 0; h < 8; ++h)
#pragma unroll
    for (int mk = 1; mk < 64; mk <<= 1) p[h] += __shfl_xor(p[h], mk, 64);
  float val = p[0];
#pragma unroll
  for (int h = 1; h < 8; ++h) val = (lane == h) ? p[h] : val;  // static idx (rule #20)
  if (lane < 8) {
    float mb = (z_mask[row] > 0.0f) ? 0.0f : -1e9f;
    bias[(size_t)lane * 262144 + row] = val * rms + mb;
  }
}

// ---------------------------------------------------------------------------
// Shared 128x128 MFMA GEMM mainloop. A [M][256] bf16 row-major, Bt [N][256]
// bf16 n-major. BK=32, 4 waves in 2x2, each wave 64x64 (4x4 16x16 C-frags).
// LDS rows padded to 40 elems (80B): 16B-aligned b128 + uniform bank spread.
// ---------------------------------------------------------------------------
DI void gemm_mainloop(const unsigned short* __restrict__ Amat,
                      const unsigned short* __restrict__ Btmat,
                      int mb, int nb, f32x4 acc[4][4],
                      unsigned short* At, unsigned short* Bts) {
  int tid = threadIdx.x, lane = tid & 63;
  int wm = (tid >> 6) >> 1, wn = (tid >> 6) & 1;
  int r16 = lane & 15, g8 = (lane >> 4) * 8;
  for (int kb = 0; kb < 256; kb += 32) {
#pragma unroll
    for (int u = 0; u < 2; ++u) {
      int c = u * 256 + tid;                 // 0..511 16B chunks
      int rrow = c >> 2, gg = (c & 3) * 8;
      *(bf16x8*)(At + rrow * 40 + gg) =
          *(const bf16x8*)(Amat + (size_t)(mb + rrow) * 256 + kb + gg);
      *(bf16x8*)(Bts + rrow * 40 + gg) =
          *(const bf16x8*)(Btmat + (size_t)(nb + rrow) * 256 + kb + gg);
    }
    __syncthreads();
    bf16x8 af[4], bfr[4];
#pragma unroll
    for (int i = 0; i < 4; ++i)
      af[i] = *(const bf16x8*)(At + (wm * 64 + i * 16 + r16) * 40 + g8);
#pragma unroll
    for (int j = 0; j < 4; ++j)
      bfr[j] = *(const bf16x8*)(Bts + (wn * 64 + j * 16 + r16) * 40 + g8);
#pragma unroll
    for (int i = 0; i < 4; ++i)
#pragma unroll
      for (int j = 0; j < 4; ++j)
        acc[i][j] = __builtin_amdgcn_mfma_f32_16x16x32_bf16(af[i], bfr[j],
                                                            acc[i][j], 0, 0, 0);
    __syncthreads();
  }
}

// GEMM 1: m_norm @ [Wq|Wk|Wv|Wg]. Epilogue scatters q,k,v to [B,H,S,D] bf16
// (head-contiguous for attention) and g (+bg) to fp32 [B,S,256].
__global__ __launch_bounds__(256) void k_gemm_qkvg(
    const unsigned short* __restrict__ m_norm, const unsigned short* __restrict__ Wt,
    const float* __restrict__ bg,
    unsigned short* __restrict__ q_ws, unsigned short* __restrict__ k_ws,
    unsigned short* __restrict__ v_ws, float* __restrict__ g_ws) {
  __shared__ unsigned short At[128 * 40];
  __shared__ unsigned short Bts[128 * 40];
  int mb = blockIdx.x * 128, nb = blockIdx.y * 128;
  f32x4 acc[4][4] = {};
  gemm_mainloop(m_norm, Wt, mb, nb, acc, At, Bts);
  int lane = threadIdx.x & 63;
  int wm = (threadIdx.x >> 6) >> 1, wn = (threadIdx.x >> 6) & 1;
  int r16 = lane & 15, rg = lane >> 4;
#pragma unroll
  for (int i = 0; i < 4; ++i)
#pragma unroll
    for (int j = 0; j < 4; ++j) {
      int n = nb + wn * 64 + j * 16 + r16;
#pragma unroll
      for (int r = 0; r < 4; ++r) {
        int mrow = mb + wm * 64 + i * 16 + rg * 4 + r;
        int bb = mrow >> 9, s = mrow & 511;
        float v = acc[i][j][r];
        if (n < 768) {
          int tsel = n >> 8, hh = (n >> 5) & 7, dd = n & 31;
          unsigned short* dst = (tsel == 0) ? q_ws : (tsel == 1) ? k_ws : v_ws;
          dst[(((size_t)bb * 8 + hh) * 512 + s) * 32 + dd] = f2bf(v);
        } else {
          int n2 = n & 255;
          g_ws[(size_t)mrow * 256 + n2] = v + bg[n2];
        }
      }
    }
}

// GEMM 2: attn_out @ Wo, epilogue (+bo)*g -> fp32 output.
__global__ __launch_bounds__(256) void k_gemm_out(
    const unsigned short* __restrict__ attn_out, const unsigned short* __restrict__ Wt_o,
    const float* __restrict__ bo, const float* __restrict__ g_ws,
    float* __restrict__ out) {
  __shared__ unsigned short At[128 * 40];
  __shared__ unsigned short Bts[128 * 40];
  int mb = blockIdx.x * 128, nb = blockIdx.y * 128;
  f32x4 acc[4][4] = {};
  gemm_mainloop(attn_out, Wt_o, mb, nb, acc, At, Bts);
  int lane = threadIdx.x & 63;
  int wm = (threadIdx.x >> 6) >> 1, wn = (threadIdx.x >> 6) & 1;
  int r16 = lane & 15, rg = lane >> 4;
#pragma unroll
  for (int i = 0; i < 4; ++i)
#pragma unroll
    for (int j = 0; j < 4; ++j) {
      int n = nb + wn * 64 + j * 16 + r16;
#pragma unroll
      for (int r = 0; r < 4; ++r) {
        int mrow = mb + wm * 64 + i * 16 + rg * 4 + r;
        out[(size_t)mrow * 256 + n] = (acc[i][j][r] + bo[n]) * g_ws[(size_t)mrow * 256 + n];
      }
    }
}

// ---------------------------------------------------------------------------
// Attention: one block per (b,h), h-major grid so 64 consecutive blocks share
// the head's bias plane / K / V in L2. 4 independent waves, each 8 q-tiles of
// 16 rows. Full 16x512 score strip in regs (128 VGPR), single-pass softmax,
// PV via per-wave LDS P-transpose + LDS-transposed V.
// ---------------------------------------------------------------------------
#define VT_LD 520  // 1040B rows: 16B aligned, banks spread 4/row
#define P_LD 40
__global__ __launch_bounds__(256, 2) void k_attn(
    const unsigned short* __restrict__ q_ws, const unsigned short* __restrict__ k_ws,
    const unsigned short* __restrict__ v_ws, const float* __restrict__ bias,
    unsigned short* __restrict__ attn_out) {
  __shared__ unsigned short Vt[32 * VT_LD];        // V^T [d][s]  (33,280 B)
  __shared__ unsigned short P_lds[4][16 * P_LD];   // per-wave P chunk (5,120 B)
  int tid = threadIdx.x;
  int wave = tid >> 6, lane = tid & 63;
  int bh = blockIdx.x;
  int h = bh >> 6, b = bh & 63;                    // h-major for L2 sharing
  size_t base = ((size_t)b * 8 + h) * (512 * 32);
  const unsigned short* qb = q_ws + base;
  const unsigned short* kb = k_ws + base;
  const unsigned short* vb = v_ws + base;
  // stage V transposed: read [s][d] coalesced, scatter to Vt[d][s]
#pragma unroll
  for (int it = 0; it < 8; ++it) {
    int idx = it * 256 + tid;
    int s = idx >> 2, d0 = (idx & 3) * 8;
    bf16x8 vv = *(const bf16x8*)(vb + s * 32 + d0);
#pragma unroll
    for (int j = 0; j < 8; ++j) Vt[(d0 + j) * VT_LD + s] = (unsigned short)vv[j];
  }
  __syncthreads();

  int r16 = lane & 15, g = lane >> 4;
  const float* biasr = bias + (size_t)h * 262144;
  unsigned short* Pl = &P_lds[wave][0];
  unsigned short* ob = attn_out + ((size_t)b * 512) * 256 + h * 32;
  const f32x4 zero = {0.f, 0.f, 0.f, 0.f};

  for (int qt = 0; qt < 8; ++qt) {
    int qbase = (wave * 8 + qt) * 16;
    // A-frag: q[qbase+l%16][d = g*8+j]
    bf16x8 qf = *(const bf16x8*)(qb + (qbase + r16) * 32 + g * 8);
    f32x4 sc[32];
#pragma unroll
    for (int t = 0; t < 32; ++t) {
      // B-frag: K^T[d=g*8+j][kcol = 16t+l%16] — 1KB fully-coalesced per instr
      bf16x8 kf = *(const bf16x8*)(kb + (t * 16 + r16) * 32 + g * 8);
      sc[t] = __builtin_amdgcn_mfma_f32_16x16x32_bf16(qf, kf, zero, 0, 0, 0);
    }
    // scale + bias, row max (rows are lane-group local: 4 shfl steps)
    float mx[4] = {-3e38f, -3e38f, -3e38f, -3e38f};
#pragma unroll
    for (int t = 0; t < 32; ++t)
#pragma unroll
      for (int r = 0; r < 4; ++r) {
        int qrow = qbase + g * 4 + r;
        float v = sc[t][r] * 0.17677669529663687f +
                  biasr[(size_t)qrow * 512 + t * 16 + r16];
        sc[t][r] = v;
        mx[r] = fmaxf(mx[r], v);
      }
#pragma unroll
    for (int r = 0; r < 4; ++r)
#pragma unroll
      for (int mk = 1; mk < 16; mk <<= 1)
        mx[r] = fmaxf(mx[r], __shfl_xor(mx[r], mk, 64));
    float sm[4] = {0.f, 0.f, 0.f, 0.f};
#pragma unroll
    for (int t = 0; t < 32; ++t)
#pragma unroll
      for (int r = 0; r < 4; ++r) {
        float e = __expf(sc[t][r] - mx[r]);
        sc[t][r] = e;
        sm[r] += e;
      }
#pragma unroll
    for (int r = 0; r < 4; ++r)
#pragma unroll
      for (int mk = 1; mk < 16; mk <<= 1) sm[r] += __shfl_xor(sm[r], mk, 64);
    float inv[4];
#pragma unroll
    for (int r = 0; r < 4; ++r) inv[r] = 1.0f / sm[r];

    // PV: per 32-k chunk, transpose P through LDS (wave-local, no barrier;
    // LDS unit is in-order per wave so WAR/RAW across chunks is safe)
    f32x4 o0 = zero, o1 = zero;
#pragma unroll
    for (int c = 0; c < 16; ++c) {
#pragma unroll
      for (int halfi = 0; halfi < 2; ++halfi) {
        int t = c * 2 + halfi;
#pragma unroll
        for (int r = 0; r < 4; ++r)
          Pl[(g * 4 + r) * P_LD + halfi * 16 + r16] = f2bf(sc[t][r] * inv[r]);
      }
      bf16x8 pf = *(const bf16x8*)(Pl + r16 * P_LD + g * 8);       // A-frag P
      bf16x8 vf0 = *(const bf16x8*)(Vt + r16 * VT_LD + c * 32 + g * 8);
      bf16x8 vf1 = *(const bf16x8*)(Vt + (r16 + 16) * VT_LD + c * 32 + g * 8);
      o0 = __builtin_amdgcn_mfma_f32_16x16x32_bf16(pf, vf0, o0, 0, 0, 0);
      o1 = __builtin_amdgcn_mfma_f32_16x16x32_bf16(pf, vf1, o1, 0, 0, 0);
    }
#pragma unroll
    for (int r = 0; r < 4; ++r) {
      int s = qbase + g * 4 + r;
      ob[(size_t)s * 256 + r16] = f2bf(o0[r]);
      ob[(size_t)s * 256 + 16 + r16] = f2bf(o1[r]);
    }
  }
}

// ---------------------------------------------------------------------------
extern "C" void kernel_launch(void* const* d_in, const int* in_sizes, int n_in,
                              void* d_out, int out_size, void* d_ws, size_t ws_size,
                              hipStream_t stream) {
  (void)in_sizes; (void)n_in; (void)out_size; (void)ws_size;
  const float* m        = (const float*)d_in[0];
  const float* z        = (const float*)d_in[1];
  const float* z_mask   = (const float*)d_in[2];
  const float* w_norm_m = (const float*)d_in[3];
  const float* w_norm_z = (const float*)d_in[4];
  const float* Wq = (const float*)d_in[5];
  const float* Wk = (const float*)d_in[6];
  const float* Wv = (const float*)d_in[7];
  const float* Wz = (const float*)d_in[8];
  const float* Wg = (const float*)d_in[9];
  const float* bg = (const float*)d_in[10];
  const float* Wo = (const float*)d_in[11];
  const float* bo = (const float*)d_in[12];
  float* out = (float*)d_out;

  char* ws = (char*)d_ws;
  size_t off = 0;
  unsigned short* m_norm  = (unsigned short*)(ws + off); off += (size_t)32768 * 256 * 2;
  unsigned short* Wt_qkvg = (unsigned short*)(ws + off); off += (size_t)1024 * 256 * 2;
  unsigned short* Wt_o    = (unsigned short*)(ws + off); off += (size_t)256 * 256 * 2;
  unsigned short* q_ws    = (unsigned short*)(ws + off); off += (size_t)64 * 8 * 512 * 32 * 2;
  unsigned short* k_ws    = (unsigned short*)(ws + off); off += (size_t)64 * 8 * 512 * 32 * 2;
  unsigned short* v_ws    = (unsigned short*)(ws + off); off += (size_t)64 * 8 * 512 * 32 * 2;
  float* g_ws             = (float*)(ws + off);          off += (size_t)32768 * 256 * 4;
  float* bias             = (float*)(ws + off);          off += (size_t)8 * 512 * 512 * 4;
  // attn_out aliases m_norm: m_norm is dead after k_gemm_qkvg. (~110 MB ws total)
  unsigned short* attn_out = m_norm;

  hipLaunchKernelGGL(k_cast_weights, dim3(1280), dim3(256), 0, stream,
                     Wq, Wk, Wv, Wg, Wo, Wt_qkvg, Wt_o);
  hipLaunchKernelGGL(k_rmsnorm_m, dim3(8192), dim3(256), 0, stream, m, w_norm_m, m_norm);
  hipLaunchKernelGGL(k_pair_bias, dim3(65536), dim3(256), 0, stream,
                     z, z_mask, w_norm_z, Wz, bias);
  hipLaunchKernelGGL(k_gemm_qkvg, dim3(256, 8), dim3(256), 0, stream,
                     m_norm, Wt_qkvg, bg, q_ws, k_ws, v_ws, g_ws);
  hipLaunchKernelGGL(k_attn, dim3(512), dim3(256), 0, stream,
                     q_ws, k_ws, v_ws, bias, attn_out);
  hipLaunchKernelGGL(k_gemm_out, dim3(256, 2), dim3(256), 0, stream,
                     attn_out, Wt_o, bo, g_ws, out);
}

// Round 2
// 321.762 us; speedup vs baseline: 1.0525x; 1.0525x over previous
//
#include <hip/hip_runtime.h>

typedef short bf16x8 __attribute__((ext_vector_type(8)));
typedef float f32x4 __attribute__((ext_vector_type(4)));

#define DI __device__ __forceinline__

static DI unsigned short f2bf(float f) {
  union { float f; unsigned u; } v; v.f = f;
  unsigned r = v.u + 0x7FFFu + ((v.u >> 16) & 1u);  // RNE
  return (unsigned short)(r >> 16);
}

// ---------------------------------------------------------------------------
// Weight prep: cast+transpose to bf16 [N][K] (n-major rows) so GEMM B-tiles
// stage as contiguous 16B rows and B-fragments are ds_read_b128-friendly.
// ---------------------------------------------------------------------------
__global__ __launch_bounds__(256) void k_cast_weights(
    const float* __restrict__ Wq, const float* __restrict__ Wk,
    const float* __restrict__ Wv, const float* __restrict__ Wg,
    const float* __restrict__ Wo,
    unsigned short* __restrict__ Wt_qkvg, unsigned short* __restrict__ Wt_o) {
  int t = blockIdx.x * 256 + threadIdx.x;
  if (t < 262144) {
    int n = t & 1023, kk = t >> 10;
    const float* W = (n < 256) ? Wq : (n < 512) ? Wk : (n < 768) ? Wv : Wg;
    Wt_qkvg[(size_t)n * 256 + kk] = f2bf(W[kk * 256 + (n & 255)]);
  } else if (t < 262144 + 65536) {
    int u = t - 262144;
    int n = u & 255, kk = u >> 8;
    Wt_o[n * 256 + kk] = f2bf(Wo[kk * 256 + n]);
  }
}

// ---------------------------------------------------------------------------
// rmsnorm(m) -> bf16. One wave per 256-elem row, float4 per lane.
// ---------------------------------------------------------------------------
__global__ __launch_bounds__(256) void k_rmsnorm_m(
    const float* __restrict__ m, const float* __restrict__ w,
    unsigned short* __restrict__ m_norm) {
  int wave = threadIdx.x >> 6, lane = threadIdx.x & 63;
  int row = blockIdx.x * 4 + wave;
  const float4 x = *(const float4*)(m + (size_t)row * 256 + lane * 4);
  float ss = x.x * x.x + x.y * x.y + x.z * x.z + x.w * x.w;
#pragma unroll
  for (int mk = 1; mk < 64; mk <<= 1) ss += __shfl_xor(ss, mk, 64);
  float rms = rsqrtf(ss * (1.0f / 256.0f) + 1e-5f);
  const float4 wv = *(const float4*)(w + lane * 4);
  ushort4 o;
  o.x = f2bf(x.x * rms * wv.x);
  o.y = f2bf(x.y * rms * wv.y);
  o.z = f2bf(x.z * rms * wv.z);
  o.w = f2bf(x.w * rms * wv.w);
  *(ushort4*)(m_norm + (size_t)row * 256 + lane * 4) = o;
}

// ---------------------------------------------------------------------------
// Pair bias: bias[h][i][j] = rmsnorm(z[i,j,:]) . (w_norm_z*Wz[:,h]) + mask.
// R1 restructure: 8 lanes per z-row (16 c-elems each), 8 rows per wave.
// ss reduce = 3 shfls; head dots via reduce-scatter = 7 shfls per 8 rows
// (vs 54 shfls PER ROW in R0 — that serial shuffle chain was the 161 us).
// Wz (4 KB) and w_norm_z read from L1 directly; no LDS, no barrier.
// ---------------------------------------------------------------------------
__global__ __launch_bounds__(256) void k_pair_bias(
    const float* __restrict__ z, const float* __restrict__ z_mask,
    const float* __restrict__ w_norm_z, const float* __restrict__ Wz,
    float* __restrict__ bias) {
  int tid = threadIdx.x;
  int wave = tid >> 6, lane = tid & 63;
  int rg = lane >> 3, ch = lane & 7;
  int row = (blockIdx.x * 4 + wave) * 8 + rg;  // 0..262143
  int c0 = ch * 16;
  const float* zr = z + (size_t)row * 128 + c0;
  float4 a0 = *(const float4*)(zr);
  float4 a1 = *(const float4*)(zr + 4);
  float4 a2 = *(const float4*)(zr + 8);
  float4 a3 = *(const float4*)(zr + 12);
  float mb = (z_mask[row] > 0.0f) ? 0.0f : -1e9f;
  const float4 w0 = *(const float4*)(w_norm_z + c0);
  const float4 w1 = *(const float4*)(w_norm_z + c0 + 4);
  const float4 w2 = *(const float4*)(w_norm_z + c0 + 8);
  const float4 w3 = *(const float4*)(w_norm_z + c0 + 12);

  float ss = a0.x * a0.x + a0.y * a0.y + a0.z * a0.z + a0.w * a0.w +
             a1.x * a1.x + a1.y * a1.y + a1.z * a1.z + a1.w * a1.w +
             a2.x * a2.x + a2.y * a2.y + a2.z * a2.z + a2.w * a2.w +
             a3.x * a3.x + a3.y * a3.y + a3.z * a3.z + a3.w * a3.w;
  ss += __shfl_xor(ss, 1, 64);
  ss += __shfl_xor(ss, 2, 64);
  ss += __shfl_xor(ss, 4, 64);
  float rms = rsqrtf(ss * (1.0f / 128.0f) + 1e-5f);

  float y[16] = {a0.x * w0.x, a0.y * w0.y, a0.z * w0.z, a0.w * w0.w,
                 a1.x * w1.x, a1.y * w1.y, a1.z * w1.z, a1.w * w1.w,
                 a2.x * w2.x, a2.y * w2.y, a2.z * w2.z, a2.w * w2.w,
                 a3.x * w3.x, a3.y * w3.y, a3.z * w3.z, a3.w * w3.w};
  f32x4 pl = {0.f, 0.f, 0.f, 0.f}, ph = {0.f, 0.f, 0.f, 0.f};
#pragma unroll
  for (int i = 0; i < 16; ++i) {
    f32x4 lo = *(const f32x4*)(Wz + (c0 + i) * 8);
    f32x4 hi = *(const f32x4*)(Wz + (c0 + i) * 8 + 4);
    pl += y[i] * lo;
    ph += y[i] * hi;
  }

  // reduce-scatter 8 head partials across the row's 8 lanes (xor 1,2,4):
  // lane ends holding the full dot for head (lane&7).
  int b0 = lane & 1, b1 = (lane >> 1) & 1, b2 = (lane >> 2) & 1;
  float A[4] = {pl[0], pl[2], ph[0], ph[2]};   // even heads 0,2,4,6
  float Bv[4] = {pl[1], pl[3], ph[1], ph[3]};  // odd heads 1,3,5,7
  float keep[4];
#pragma unroll
  for (int i = 0; i < 4; ++i) {
    float send = b0 ? A[i] : Bv[i];
    float recv = __shfl_xor(send, 1, 64);
    keep[i] = (b0 ? Bv[i] : A[i]) + recv;      // head 2i + b0
  }
  float s2x = b1 ? keep[0] : keep[1];
  float s2y = b1 ? keep[2] : keep[3];
  float r2x = __shfl_xor(s2x, 2, 64);
  float r2y = __shfl_xor(s2y, 2, 64);
  float k2x = (b1 ? keep[1] : keep[0]) + r2x;  // head (lane&3)
  float k2y = (b1 ? keep[3] : keep[2]) + r2y;  // head 4 + (lane&3)
  float s3 = b2 ? k2x : k2y;
  float r3 = __shfl_xor(s3, 4, 64);
  float fin = (b2 ? k2y : k2x) + r3;           // head (lane&7)

  bias[(size_t)ch * 262144 + row] = fin * rms + mb;
}

// ---------------------------------------------------------------------------
// Shared 128x128 MFMA GEMM mainloop. A [M][256] bf16 row-major, Bt [N][256]
// bf16 n-major. BK=32, 4 waves in 2x2, each wave 64x64 (4x4 16x16 C-frags).
// LDS rows padded to 40 elems (80B): 16B-aligned b128 + uniform bank spread.
// ---------------------------------------------------------------------------
DI void gemm_mainloop(const unsigned short* __restrict__ Amat,
                      const unsigned short* __restrict__ Btmat,
                      int mb, int nb, f32x4 acc[4][4],
                      unsigned short* At, unsigned short* Bts) {
  int tid = threadIdx.x, lane = tid & 63;
  int wm = (tid >> 6) >> 1, wn = (tid >> 6) & 1;
  int r16 = lane & 15, g8 = (lane >> 4) * 8;
  for (int kb = 0; kb < 256; kb += 32) {
#pragma unroll
    for (int u = 0; u < 2; ++u) {
      int c = u * 256 + tid;                 // 0..511 16B chunks
      int rrow = c >> 2, gg = (c & 3) * 8;
      *(bf16x8*)(At + rrow * 40 + gg) =
          *(const bf16x8*)(Amat + (size_t)(mb + rrow) * 256 + kb + gg);
      *(bf16x8*)(Bts + rrow * 40 + gg) =
          *(const bf16x8*)(Btmat + (size_t)(nb + rrow) * 256 + kb + gg);
    }
    __syncthreads();
    bf16x8 af[4], bfr[4];
#pragma unroll
    for (int i = 0; i < 4; ++i)
      af[i] = *(const bf16x8*)(At + (wm * 64 + i * 16 + r16) * 40 + g8);
#pragma unroll
    for (int j = 0; j < 4; ++j)
      bfr[j] = *(const bf16x8*)(Bts + (wn * 64 + j * 16 + r16) * 40 + g8);
#pragma unroll
    for (int i = 0; i < 4; ++i)
#pragma unroll
      for (int j = 0; j < 4; ++j)
        acc[i][j] = __builtin_amdgcn_mfma_f32_16x16x32_bf16(af[i], bfr[j],
                                                            acc[i][j], 0, 0, 0);
    __syncthreads();
  }
}

// GEMM 1: m_norm @ [Wq|Wk|Wv|Wg]. Epilogue scatters q,k,v to [B,H,S,D] bf16
// (head-contiguous for attention) and g (+bg) to fp32 [B,S,256].
__global__ __launch_bounds__(256) void k_gemm_qkvg(
    const unsigned short* __restrict__ m_norm, const unsigned short* __restrict__ Wt,
    const float* __restrict__ bg,
    unsigned short* __restrict__ q_ws, unsigned short* __restrict__ k_ws,
    unsigned short* __restrict__ v_ws, float* __restrict__ g_ws) {
  __shared__ unsigned short At[128 * 40];
  __shared__ unsigned short Bts[128 * 40];
  int mb = blockIdx.x * 128, nb = blockIdx.y * 128;
  f32x4 acc[4][4] = {};
  gemm_mainloop(m_norm, Wt, mb, nb, acc, At, Bts);
  int lane = threadIdx.x & 63;
  int wm = (threadIdx.x >> 6) >> 1, wn = (threadIdx.x >> 6) & 1;
  int r16 = lane & 15, rg = lane >> 4;
#pragma unroll
  for (int i = 0; i < 4; ++i)
#pragma unroll
    for (int j = 0; j < 4; ++j) {
      int n = nb + wn * 64 + j * 16 + r16;
#pragma unroll
      for (int r = 0; r < 4; ++r) {
        int mrow = mb + wm * 64 + i * 16 + rg * 4 + r;
        int bb = mrow >> 9, s = mrow & 511;
        float v = acc[i][j][r];
        if (n < 768) {
          int tsel = n >> 8, hh = (n >> 5) & 7, dd = n & 31;
          unsigned short* dst = (tsel == 0) ? q_ws : (tsel == 1) ? k_ws : v_ws;
          dst[(((size_t)bb * 8 + hh) * 512 + s) * 32 + dd] = f2bf(v);
        } else {
          int n2 = n & 255;
          g_ws[(size_t)mrow * 256 + n2] = v + bg[n2];
        }
      }
    }
}

// GEMM 2: attn_out @ Wo, epilogue (+bo)*g -> fp32 output.
__global__ __launch_bounds__(256) void k_gemm_out(
    const unsigned short* __restrict__ attn_out, const unsigned short* __restrict__ Wt_o,
    const float* __restrict__ bo, const float* __restrict__ g_ws,
    float* __restrict__ out) {
  __shared__ unsigned short At[128 * 40];
  __shared__ unsigned short Bts[128 * 40];
  int mb = blockIdx.x * 128, nb = blockIdx.y * 128;
  f32x4 acc[4][4] = {};
  gemm_mainloop(attn_out, Wt_o, mb, nb, acc, At, Bts);
  int lane = threadIdx.x & 63;
  int wm = (threadIdx.x >> 6) >> 1, wn = (threadIdx.x >> 6) & 1;
  int r16 = lane & 15, rg = lane >> 4;
#pragma unroll
  for (int i = 0; i < 4; ++i)
#pragma unroll
    for (int j = 0; j < 4; ++j) {
      int n = nb + wn * 64 + j * 16 + r16;
#pragma unroll
      for (int r = 0; r < 4; ++r) {
        int mrow = mb + wm * 64 + i * 16 + rg * 4 + r;
        out[(size_t)mrow * 256 + n] = (acc[i][j][r] + bo[n]) * g_ws[(size_t)mrow * 256 + n];
      }
    }
}

// ---------------------------------------------------------------------------
// Attention: one block per (b,h), h-major grid so 64 consecutive blocks share
// the head's bias plane / K / V in L2. 4 independent waves, each 8 q-tiles of
// 16 rows. Full 16x512 score strip in regs (128 VGPR), single-pass softmax,
// PV via per-wave LDS P-transpose + LDS-transposed V.
// ---------------------------------------------------------------------------
#define VT_LD 520  // 1040B rows: 16B aligned, banks spread 4/row
#define P_LD 40
__global__ __launch_bounds__(256, 2) void k_attn(
    const unsigned short* __restrict__ q_ws, const unsigned short* __restrict__ k_ws,
    const unsigned short* __restrict__ v_ws, const float* __restrict__ bias,
    unsigned short* __restrict__ attn_out) {
  __shared__ unsigned short Vt[32 * VT_LD];        // V^T [d][s]  (33,280 B)
  __shared__ unsigned short P_lds[4][16 * P_LD];   // per-wave P chunk (5,120 B)
  int tid = threadIdx.x;
  int wave = tid >> 6, lane = tid & 63;
  int bh = blockIdx.x;
  int h = bh >> 6, b = bh & 63;                    // h-major for L2 sharing
  size_t base = ((size_t)b * 8 + h) * (512 * 32);
  const unsigned short* qb = q_ws + base;
  const unsigned short* kb = k_ws + base;
  const unsigned short* vb = v_ws + base;
  // stage V transposed: read [s][d] coalesced, scatter to Vt[d][s]
#pragma unroll
  for (int it = 0; it < 8; ++it) {
    int idx = it * 256 + tid;
    int s = idx >> 2, d0 = (idx & 3) * 8;
    bf16x8 vv = *(const bf16x8*)(vb + s * 32 + d0);
#pragma unroll
    for (int j = 0; j < 8; ++j) Vt[(d0 + j) * VT_LD + s] = (unsigned short)vv[j];
  }
  __syncthreads();

  int r16 = lane & 15, g = lane >> 4;
  const float* biasr = bias + (size_t)h * 262144;
  unsigned short* Pl = &P_lds[wave][0];
  unsigned short* ob = attn_out + ((size_t)b * 512) * 256 + h * 32;
  const f32x4 zero = {0.f, 0.f, 0.f, 0.f};

  for (int qt = 0; qt < 8; ++qt) {
    int qbase = (wave * 8 + qt) * 16;
    // A-frag: q[qbase+l%16][d = g*8+j]
    bf16x8 qf = *(const bf16x8*)(qb + (qbase + r16) * 32 + g * 8);
    f32x4 sc[32];
#pragma unroll
    for (int t = 0; t < 32; ++t) {
      // B-frag: K^T[d=g*8+j][kcol = 16t+l%16] — 1KB fully-coalesced per instr
      bf16x8 kf = *(const bf16x8*)(kb + (t * 16 + r16) * 32 + g * 8);
      sc[t] = __builtin_amdgcn_mfma_f32_16x16x32_bf16(qf, kf, zero, 0, 0, 0);
    }
    // scale + bias, row max (rows are lane-group local: 4 shfl steps)
    float mx[4] = {-3e38f, -3e38f, -3e38f, -3e38f};
#pragma unroll
    for (int t = 0; t < 32; ++t)
#pragma unroll
      for (int r = 0; r < 4; ++r) {
        int qrow = qbase + g * 4 + r;
        float v = sc[t][r] * 0.17677669529663687f +
                  biasr[(size_t)qrow * 512 + t * 16 + r16];
        sc[t][r] = v;
        mx[r] = fmaxf(mx[r], v);
      }
#pragma unroll
    for (int r = 0; r < 4; ++r)
#pragma unroll
      for (int mk = 1; mk < 16; mk <<= 1)
        mx[r] = fmaxf(mx[r], __shfl_xor(mx[r], mk, 64));
    float sm[4] = {0.f, 0.f, 0.f, 0.f};
#pragma unroll
    for (int t = 0; t < 32; ++t)
#pragma unroll
      for (int r = 0; r < 4; ++r) {
        float e = __expf(sc[t][r] - mx[r]);
        sc[t][r] = e;
        sm[r] += e;
      }
#pragma unroll
    for (int r = 0; r < 4; ++r)
#pragma unroll
      for (int mk = 1; mk < 16; mk <<= 1) sm[r] += __shfl_xor(sm[r], mk, 64);
    float inv[4];
#pragma unroll
    for (int r = 0; r < 4; ++r) inv[r] = 1.0f / sm[r];

    // PV: per 32-k chunk, transpose P through LDS (wave-local, no barrier;
    // LDS unit is in-order per wave so WAR/RAW across chunks is safe)
    f32x4 o0 = zero, o1 = zero;
#pragma unroll
    for (int c = 0; c < 16; ++c) {
#pragma unroll
      for (int halfi = 0; halfi < 2; ++halfi) {
        int t = c * 2 + halfi;
#pragma unroll
        for (int r = 0; r < 4; ++r)
          Pl[(g * 4 + r) * P_LD + halfi * 16 + r16] = f2bf(sc[t][r] * inv[r]);
      }
      bf16x8 pf = *(const bf16x8*)(Pl + r16 * P_LD + g * 8);       // A-frag P
      bf16x8 vf0 = *(const bf16x8*)(Vt + r16 * VT_LD + c * 32 + g * 8);
      bf16x8 vf1 = *(const bf16x8*)(Vt + (r16 + 16) * VT_LD + c * 32 + g * 8);
      o0 = __builtin_amdgcn_mfma_f32_16x16x32_bf16(pf, vf0, o0, 0, 0, 0);
      o1 = __builtin_amdgcn_mfma_f32_16x16x32_bf16(pf, vf1, o1, 0, 0, 0);
    }
#pragma unroll
    for (int r = 0; r < 4; ++r) {
      int s = qbase + g * 4 + r;
      ob[(size_t)s * 256 + r16] = f2bf(o0[r]);
      ob[(size_t)s * 256 + 16 + r16] = f2bf(o1[r]);
    }
  }
}

// ---------------------------------------------------------------------------
extern "C" void kernel_launch(void* const* d_in, const int* in_sizes, int n_in,
                              void* d_out, int out_size, void* d_ws, size_t ws_size,
                              hipStream_t stream) {
  (void)in_sizes; (void)n_in; (void)out_size; (void)ws_size;
  const float* m        = (const float*)d_in[0];
  const float* z        = (const float*)d_in[1];
  const float* z_mask   = (const float*)d_in[2];
  const float* w_norm_m = (const float*)d_in[3];
  const float* w_norm_z = (const float*)d_in[4];
  const float* Wq = (const float*)d_in[5];
  const float* Wk = (const float*)d_in[6];
  const float* Wv = (const float*)d_in[7];
  const float* Wz = (const float*)d_in[8];
  const float* Wg = (const float*)d_in[9];
  const float* bg = (const float*)d_in[10];
  const float* Wo = (const float*)d_in[11];
  const float* bo = (const float*)d_in[12];
  float* out = (float*)d_out;

  char* ws = (char*)d_ws;
  size_t off = 0;
  unsigned short* m_norm  = (unsigned short*)(ws + off); off += (size_t)32768 * 256 * 2;
  unsigned short* Wt_qkvg = (unsigned short*)(ws + off); off += (size_t)1024 * 256 * 2;
  unsigned short* Wt_o    = (unsigned short*)(ws + off); off += (size_t)256 * 256 * 2;
  unsigned short* q_ws    = (unsigned short*)(ws + off); off += (size_t)64 * 8 * 512 * 32 * 2;
  unsigned short* k_ws    = (unsigned short*)(ws + off); off += (size_t)64 * 8 * 512 * 32 * 2;
  unsigned short* v_ws    = (unsigned short*)(ws + off); off += (size_t)64 * 8 * 512 * 32 * 2;
  float* g_ws             = (float*)(ws + off);          off += (size_t)32768 * 256 * 4;
  float* bias             = (float*)(ws + off);          off += (size_t)8 * 512 * 512 * 4;
  // attn_out aliases m_norm: m_norm is dead after k_gemm_qkvg. (~110 MB ws total)
  unsigned short* attn_out = m_norm;

  hipLaunchKernelGGL(k_cast_weights, dim3(1280), dim3(256), 0, stream,
                     Wq, Wk, Wv, Wg, Wo, Wt_qkvg, Wt_o);
  hipLaunchKernelGGL(k_rmsnorm_m, dim3(8192), dim3(256), 0, stream, m, w_norm_m, m_norm);
  hipLaunchKernelGGL(k_pair_bias, dim3(8192), dim3(256), 0, stream,
                     z, z_mask, w_norm_z, Wz, bias);
  hipLaunchKernelGGL(k_gemm_qkvg, dim3(256, 8), dim3(256), 0, stream,
                     m_norm, Wt_qkvg, bg, q_ws, k_ws, v_ws, g_ws);
  hipLaunchKernelGGL(k_attn, dim3(512), dim3(256), 0, stream,
                     q_ws, k_ws, v_ws, bias, attn_out);
  hipLaunchKernelGGL(k_gemm_out, dim3(256, 2), dim3(256), 0, stream,
                     attn_out, Wt_o, bo, g_ws, out);
}

// Round 3
// 244.171 us; speedup vs baseline: 1.3869x; 1.3178x over previous
//
#include <hip/hip_runtime.h>

typedef short bf16x8 __attribute__((ext_vector_type(8)));
typedef float f32x4 __attribute__((ext_vector_type(4)));

#define DI __device__ __forceinline__

static DI unsigned short f2bf(float f) {
  union { float f; unsigned u; } v; v.f = f;
  unsigned r = v.u + 0x7FFFu + ((v.u >> 16) & 1u);  // RNE
  return (unsigned short)(r >> 16);
}

// ---------------------------------------------------------------------------
// Weight prep: cast+transpose to bf16 [N][K] (n-major rows) so GEMM B-tiles
// stage as contiguous 16B rows and B-fragments are ds_read_b128-friendly.
// ---------------------------------------------------------------------------
__global__ __launch_bounds__(256) void k_cast_weights(
    const float* __restrict__ Wq, const float* __restrict__ Wk,
    const float* __restrict__ Wv, const float* __restrict__ Wg,
    const float* __restrict__ Wo,
    unsigned short* __restrict__ Wt_qkvg, unsigned short* __restrict__ Wt_o) {
  int t = blockIdx.x * 256 + threadIdx.x;
  if (t < 262144) {
    int n = t & 1023, kk = t >> 10;
    const float* W = (n < 256) ? Wq : (n < 512) ? Wk : (n < 768) ? Wv : Wg;
    Wt_qkvg[(size_t)n * 256 + kk] = f2bf(W[kk * 256 + (n & 255)]);
  } else if (t < 262144 + 65536) {
    int u = t - 262144;
    int n = u & 255, kk = u >> 8;
    Wt_o[n * 256 + kk] = f2bf(Wo[kk * 256 + n]);
  }
}

// ---------------------------------------------------------------------------
// rmsnorm(m) -> bf16. One wave per 256-elem row, float4 per lane.
// ---------------------------------------------------------------------------
__global__ __launch_bounds__(256) void k_rmsnorm_m(
    const float* __restrict__ m, const float* __restrict__ w,
    unsigned short* __restrict__ m_norm) {
  int wave = threadIdx.x >> 6, lane = threadIdx.x & 63;
  int row = blockIdx.x * 4 + wave;
  const float4 x = *(const float4*)(m + (size_t)row * 256 + lane * 4);
  float ss = x.x * x.x + x.y * x.y + x.z * x.z + x.w * x.w;
#pragma unroll
  for (int mk = 1; mk < 64; mk <<= 1) ss += __shfl_xor(ss, mk, 64);
  float rms = rsqrtf(ss * (1.0f / 256.0f) + 1e-5f);
  const float4 wv = *(const float4*)(w + lane * 4);
  ushort4 o;
  o.x = f2bf(x.x * rms * wv.x);
  o.y = f2bf(x.y * rms * wv.y);
  o.z = f2bf(x.z * rms * wv.z);
  o.w = f2bf(x.w * rms * wv.w);
  *(ushort4*)(m_norm + (size_t)row * 256 + lane * 4) = o;
}

// ---------------------------------------------------------------------------
// Pair bias: bias[h][i][j] = rmsnorm(z[i,j,:]) . (w_norm_z*Wz[:,h]) + mask.
// R2: fully-coalesced streaming. 32-lane half-wave per z-row, float4/lane ->
// each wave-instruction reads 1KB CONTIGUOUS (16 lines, every byte used).
// R1's stride-64B 16B/lane pattern touched 64 lines per instr using 16B each
// (4x line amplification, 550 GB/s plateau). Grid-stride: Wz slice + w_norm_z
// held in regs across 8 row-iterations.
// ---------------------------------------------------------------------------
__global__ __launch_bounds__(256) void k_pair_bias(
    const float* __restrict__ z, const float* __restrict__ z_mask,
    const float* __restrict__ w_norm_z, const float* __restrict__ Wz,
    float* __restrict__ bias) {
  int gw = blockIdx.x * 4 + (threadIdx.x >> 6);   // global wave 0..16383
  int lane = threadIdx.x & 63;
  int half = lane >> 5, li = lane & 31;
  // per-lane Wz slice: rows 4li..4li+3, all 8 heads (32 regs, loop-invariant)
  f32x4 wzl[4], wzh[4];
#pragma unroll
  for (int i = 0; i < 4; ++i) {
    wzl[i] = *(const f32x4*)(Wz + (li * 4 + i) * 8);
    wzh[i] = *(const f32x4*)(Wz + (li * 4 + i) * 8 + 4);
  }
  const float4 wn = *(const float4*)(w_norm_z + li * 4);

  for (int it = 0; it < 8; ++it) {
    int row = it * 32768 + gw * 2 + half;
    const float4 a = *(const float4*)(z + (size_t)row * 128 + li * 4);
    float mb = (z_mask[row] > 0.0f) ? 0.0f : -1e9f;

    float ss = a.x * a.x + a.y * a.y + a.z * a.z + a.w * a.w;
#pragma unroll
    for (int mk = 1; mk < 32; mk <<= 1) ss += __shfl_xor(ss, mk, 64);
    float rms = rsqrtf(ss * (1.0f / 128.0f) + 1e-5f);

    float y0 = a.x * wn.x, y1 = a.y * wn.y, y2 = a.z * wn.z, y3 = a.w * wn.w;
    f32x4 pl = y0 * wzl[0] + y1 * wzl[1] + y2 * wzl[2] + y3 * wzl[3];
    f32x4 ph = y0 * wzh[0] + y1 * wzh[1] + y2 * wzh[2] + y3 * wzh[3];

    // reduce-scatter 8 head partials across the half's 32 lanes
    int b0 = li & 1, b1 = (li >> 1) & 1, b2 = (li >> 2) & 1;
    float A[4] = {pl[0], pl[2], ph[0], ph[2]};   // even heads 0,2,4,6
    float Bv[4] = {pl[1], pl[3], ph[1], ph[3]};  // odd heads 1,3,5,7
    float keep[4];
#pragma unroll
    for (int i = 0; i < 4; ++i) {
      float send = b0 ? A[i] : Bv[i];
      float recv = __shfl_xor(send, 1, 64);
      keep[i] = (b0 ? Bv[i] : A[i]) + recv;      // head 2i + b0
    }
    float s2x = b1 ? keep[0] : keep[1];
    float s2y = b1 ? keep[2] : keep[3];
    float r2x = __shfl_xor(s2x, 2, 64);
    float r2y = __shfl_xor(s2y, 2, 64);
    float k2x = (b1 ? keep[1] : keep[0]) + r2x;  // head (li&3)
    float k2y = (b1 ? keep[3] : keep[2]) + r2y;  // head 4 + (li&3)
    float s3 = b2 ? k2x : k2y;
    float r3 = __shfl_xor(s3, 4, 64);
    float fin = (b2 ? k2y : k2x) + r3;           // head (li&7), 8-lane group sum
    fin += __shfl_xor(fin, 8, 64);               // 16-lane group
    fin += __shfl_xor(fin, 16, 64);              // full 32-lane row sum

    if (li < 8) bias[(size_t)li * 262144 + row] = fin * rms + mb;
  }
}

// ---------------------------------------------------------------------------
// Shared 128x128 MFMA GEMM mainloop. A [M][256] bf16 row-major, Bt [N][256]
// bf16 n-major. BK=32, 4 waves in 2x2, each wave 64x64 (4x4 16x16 C-frags).
// LDS rows padded to 40 elems (80B): 16B-aligned b128 + uniform bank spread.
// ---------------------------------------------------------------------------
DI void gemm_mainloop(const unsigned short* __restrict__ Amat,
                      const unsigned short* __restrict__ Btmat,
                      int mb, int nb, f32x4 acc[4][4],
                      unsigned short* At, unsigned short* Bts) {
  int tid = threadIdx.x, lane = tid & 63;
  int wm = (tid >> 6) >> 1, wn = (tid >> 6) & 1;
  int r16 = lane & 15, g8 = (lane >> 4) * 8;
  for (int kb = 0; kb < 256; kb += 32) {
#pragma unroll
    for (int u = 0; u < 2; ++u) {
      int c = u * 256 + tid;                 // 0..511 16B chunks
      int rrow = c >> 2, gg = (c & 3) * 8;
      *(bf16x8*)(At + rrow * 40 + gg) =
          *(const bf16x8*)(Amat + (size_t)(mb + rrow) * 256 + kb + gg);
      *(bf16x8*)(Bts + rrow * 40 + gg) =
          *(const bf16x8*)(Btmat + (size_t)(nb + rrow) * 256 + kb + gg);
    }
    __syncthreads();
    bf16x8 af[4], bfr[4];
#pragma unroll
    for (int i = 0; i < 4; ++i)
      af[i] = *(const bf16x8*)(At + (wm * 64 + i * 16 + r16) * 40 + g8);
#pragma unroll
    for (int j = 0; j < 4; ++j)
      bfr[j] = *(const bf16x8*)(Bts + (wn * 64 + j * 16 + r16) * 40 + g8);
#pragma unroll
    for (int i = 0; i < 4; ++i)
#pragma unroll
      for (int j = 0; j < 4; ++j)
        acc[i][j] = __builtin_amdgcn_mfma_f32_16x16x32_bf16(af[i], bfr[j],
                                                            acc[i][j], 0, 0, 0);
    __syncthreads();
  }
}

// GEMM 1: m_norm @ [Wq|Wk|Wv|Wg]. Epilogue scatters q,k,v to [B,H,S,D] bf16
// (head-contiguous for attention) and g (+bg) to fp32 [B,S,256].
__global__ __launch_bounds__(256) void k_gemm_qkvg(
    const unsigned short* __restrict__ m_norm, const unsigned short* __restrict__ Wt,
    const float* __restrict__ bg,
    unsigned short* __restrict__ q_ws, unsigned short* __restrict__ k_ws,
    unsigned short* __restrict__ v_ws, float* __restrict__ g_ws) {
  __shared__ unsigned short At[128 * 40];
  __shared__ unsigned short Bts[128 * 40];
  int mb = blockIdx.x * 128, nb = blockIdx.y * 128;
  f32x4 acc[4][4] = {};
  gemm_mainloop(m_norm, Wt, mb, nb, acc, At, Bts);
  int lane = threadIdx.x & 63;
  int wm = (threadIdx.x >> 6) >> 1, wn = (threadIdx.x >> 6) & 1;
  int r16 = lane & 15, rg = lane >> 4;
#pragma unroll
  for (int i = 0; i < 4; ++i)
#pragma unroll
    for (int j = 0; j < 4; ++j) {
      int n = nb + wn * 64 + j * 16 + r16;
#pragma unroll
      for (int r = 0; r < 4; ++r) {
        int mrow = mb + wm * 64 + i * 16 + rg * 4 + r;
        int bb = mrow >> 9, s = mrow & 511;
        float v = acc[i][j][r];
        if (n < 768) {
          int tsel = n >> 8, hh = (n >> 5) & 7, dd = n & 31;
          unsigned short* dst = (tsel == 0) ? q_ws : (tsel == 1) ? k_ws : v_ws;
          dst[(((size_t)bb * 8 + hh) * 512 + s) * 32 + dd] = f2bf(v);
        } else {
          int n2 = n & 255;
          g_ws[(size_t)mrow * 256 + n2] = v + bg[n2];
        }
      }
    }
}

// GEMM 2: attn_out @ Wo, epilogue (+bo)*g -> fp32 output.
__global__ __launch_bounds__(256) void k_gemm_out(
    const unsigned short* __restrict__ attn_out, const unsigned short* __restrict__ Wt_o,
    const float* __restrict__ bo, const float* __restrict__ g_ws,
    float* __restrict__ out) {
  __shared__ unsigned short At[128 * 40];
  __shared__ unsigned short Bts[128 * 40];
  int mb = blockIdx.x * 128, nb = blockIdx.y * 128;
  f32x4 acc[4][4] = {};
  gemm_mainloop(attn_out, Wt_o, mb, nb, acc, At, Bts);
  int lane = threadIdx.x & 63;
  int wm = (threadIdx.x >> 6) >> 1, wn = (threadIdx.x >> 6) & 1;
  int r16 = lane & 15, rg = lane >> 4;
#pragma unroll
  for (int i = 0; i < 4; ++i)
#pragma unroll
    for (int j = 0; j < 4; ++j) {
      int n = nb + wn * 64 + j * 16 + r16;
#pragma unroll
      for (int r = 0; r < 4; ++r) {
        int mrow = mb + wm * 64 + i * 16 + rg * 4 + r;
        out[(size_t)mrow * 256 + n] = (acc[i][j][r] + bo[n]) * g_ws[(size_t)mrow * 256 + n];
      }
    }
}

// ---------------------------------------------------------------------------
// Attention: one block per (b,h), h-major grid so 64 consecutive blocks share
// the head's bias plane / K / V in L2. 4 independent waves, each 8 q-tiles of
// 16 rows. Full 16x512 score strip in regs (128 VGPR), single-pass softmax,
// PV via per-wave LDS P-transpose + LDS-transposed V.
// ---------------------------------------------------------------------------
#define VT_LD 520  // 1040B rows: 16B aligned, banks spread 4/row
#define P_LD 40
__global__ __launch_bounds__(256, 2) void k_attn(
    const unsigned short* __restrict__ q_ws, const unsigned short* __restrict__ k_ws,
    const unsigned short* __restrict__ v_ws, const float* __restrict__ bias,
    unsigned short* __restrict__ attn_out) {
  __shared__ unsigned short Vt[32 * VT_LD];        // V^T [d][s]  (33,280 B)
  __shared__ unsigned short P_lds[4][16 * P_LD];   // per-wave P chunk (5,120 B)
  int tid = threadIdx.x;
  int wave = tid >> 6, lane = tid & 63;
  int bh = blockIdx.x;
  int h = bh >> 6, b = bh & 63;                    // h-major for L2 sharing
  size_t base = ((size_t)b * 8 + h) * (512 * 32);
  const unsigned short* qb = q_ws + base;
  const unsigned short* kb = k_ws + base;
  const unsigned short* vb = v_ws + base;
  // stage V transposed: read [s][d] coalesced, scatter to Vt[d][s]
#pragma unroll
  for (int it = 0; it < 8; ++it) {
    int idx = it * 256 + tid;
    int s = idx >> 2, d0 = (idx & 3) * 8;
    bf16x8 vv = *(const bf16x8*)(vb + s * 32 + d0);
#pragma unroll
    for (int j = 0; j < 8; ++j) Vt[(d0 + j) * VT_LD + s] = (unsigned short)vv[j];
  }
  __syncthreads();

  int r16 = lane & 15, g = lane >> 4;
  const float* biasr = bias + (size_t)h * 262144;
  unsigned short* Pl = &P_lds[wave][0];
  unsigned short* ob = attn_out + ((size_t)b * 512) * 256 + h * 32;
  const f32x4 zero = {0.f, 0.f, 0.f, 0.f};

  for (int qt = 0; qt < 8; ++qt) {
    int qbase = (wave * 8 + qt) * 16;
    // A-frag: q[qbase+l%16][d = g*8+j]
    bf16x8 qf = *(const bf16x8*)(qb + (qbase + r16) * 32 + g * 8);
    f32x4 sc[32];
#pragma unroll
    for (int t = 0; t < 32; ++t) {
      // B-frag: K^T[d=g*8+j][kcol = 16t+l%16] — 1KB fully-coalesced per instr
      bf16x8 kf = *(const bf16x8*)(kb + (t * 16 + r16) * 32 + g * 8);
      sc[t] = __builtin_amdgcn_mfma_f32_16x16x32_bf16(qf, kf, zero, 0, 0, 0);
    }
    // scale + bias, row max (rows are lane-group local: 4 shfl steps)
    float mx[4] = {-3e38f, -3e38f, -3e38f, -3e38f};
#pragma unroll
    for (int t = 0; t < 32; ++t)
#pragma unroll
      for (int r = 0; r < 4; ++r) {
        int qrow = qbase + g * 4 + r;
        float v = sc[t][r] * 0.17677669529663687f +
                  biasr[(size_t)qrow * 512 + t * 16 + r16];
        sc[t][r] = v;
        mx[r] = fmaxf(mx[r], v);
      }
#pragma unroll
    for (int r = 0; r < 4; ++r)
#pragma unroll
      for (int mk = 1; mk < 16; mk <<= 1)
        mx[r] = fmaxf(mx[r], __shfl_xor(mx[r], mk, 64));
    float sm[4] = {0.f, 0.f, 0.f, 0.f};
#pragma unroll
    for (int t = 0; t < 32; ++t)
#pragma unroll
      for (int r = 0; r < 4; ++r) {
        float e = __expf(sc[t][r] - mx[r]);
        sc[t][r] = e;
        sm[r] += e;
      }
#pragma unroll
    for (int r = 0; r < 4; ++r)
#pragma unroll
      for (int mk = 1; mk < 16; mk <<= 1) sm[r] += __shfl_xor(sm[r], mk, 64);
    float inv[4];
#pragma unroll
    for (int r = 0; r < 4; ++r) inv[r] = 1.0f / sm[r];

    // PV: per 32-k chunk, transpose P through LDS (wave-local, no barrier;
    // LDS unit is in-order per wave so WAR/RAW across chunks is safe)
    f32x4 o0 = zero, o1 = zero;
#pragma unroll
    for (int c = 0; c < 16; ++c) {
#pragma unroll
      for (int halfi = 0; halfi < 2; ++halfi) {
        int t = c * 2 + halfi;
#pragma unroll
        for (int r = 0; r < 4; ++r)
          Pl[(g * 4 + r) * P_LD + halfi * 16 + r16] = f2bf(sc[t][r] * inv[r]);
      }
      bf16x8 pf = *(const bf16x8*)(Pl + r16 * P_LD + g * 8);       // A-frag P
      bf16x8 vf0 = *(const bf16x8*)(Vt + r16 * VT_LD + c * 32 + g * 8);
      bf16x8 vf1 = *(const bf16x8*)(Vt + (r16 + 16) * VT_LD + c * 32 + g * 8);
      o0 = __builtin_amdgcn_mfma_f32_16x16x32_bf16(pf, vf0, o0, 0, 0, 0);
      o1 = __builtin_amdgcn_mfma_f32_16x16x32_bf16(pf, vf1, o1, 0, 0, 0);
    }
#pragma unroll
    for (int r = 0; r < 4; ++r) {
      int s = qbase + g * 4 + r;
      ob[(size_t)s * 256 + r16] = f2bf(o0[r]);
      ob[(size_t)s * 256 + 16 + r16] = f2bf(o1[r]);
    }
  }
}

// ---------------------------------------------------------------------------
extern "C" void kernel_launch(void* const* d_in, const int* in_sizes, int n_in,
                              void* d_out, int out_size, void* d_ws, size_t ws_size,
                              hipStream_t stream) {
  (void)in_sizes; (void)n_in; (void)out_size; (void)ws_size;
  const float* m        = (const float*)d_in[0];
  const float* z        = (const float*)d_in[1];
  const float* z_mask   = (const float*)d_in[2];
  const float* w_norm_m = (const float*)d_in[3];
  const float* w_norm_z = (const float*)d_in[4];
  const float* Wq = (const float*)d_in[5];
  const float* Wk = (const float*)d_in[6];
  const float* Wv = (const float*)d_in[7];
  const float* Wz = (const float*)d_in[8];
  const float* Wg = (const float*)d_in[9];
  const float* bg = (const float*)d_in[10];
  const float* Wo = (const float*)d_in[11];
  const float* bo = (const float*)d_in[12];
  float* out = (float*)d_out;

  char* ws = (char*)d_ws;
  size_t off = 0;
  unsigned short* m_norm  = (unsigned short*)(ws + off); off += (size_t)32768 * 256 * 2;
  unsigned short* Wt_qkvg = (unsigned short*)(ws + off); off += (size_t)1024 * 256 * 2;
  unsigned short* Wt_o    = (unsigned short*)(ws + off); off += (size_t)256 * 256 * 2;
  unsigned short* q_ws    = (unsigned short*)(ws + off); off += (size_t)64 * 8 * 512 * 32 * 2;
  unsigned short* k_ws    = (unsigned short*)(ws + off); off += (size_t)64 * 8 * 512 * 32 * 2;
  unsigned short* v_ws    = (unsigned short*)(ws + off); off += (size_t)64 * 8 * 512 * 32 * 2;
  float* g_ws             = (float*)(ws + off);          off += (size_t)32768 * 256 * 4;
  float* bias             = (float*)(ws + off);          off += (size_t)8 * 512 * 512 * 4;
  // attn_out aliases m_norm: m_norm is dead after k_gemm_qkvg. (~110 MB ws total)
  unsigned short* attn_out = m_norm;

  hipLaunchKernelGGL(k_cast_weights, dim3(1280), dim3(256), 0, stream,
                     Wq, Wk, Wv, Wg, Wo, Wt_qkvg, Wt_o);
  hipLaunchKernelGGL(k_rmsnorm_m, dim3(8192), dim3(256), 0, stream, m, w_norm_m, m_norm);
  hipLaunchKernelGGL(k_pair_bias, dim3(4096), dim3(256), 0, stream,
                     z, z_mask, w_norm_z, Wz, bias);
  hipLaunchKernelGGL(k_gemm_qkvg, dim3(256, 8), dim3(256), 0, stream,
                     m_norm, Wt_qkvg, bg, q_ws, k_ws, v_ws, g_ws);
  hipLaunchKernelGGL(k_attn, dim3(512), dim3(256), 0, stream,
                     q_ws, k_ws, v_ws, bias, attn_out);
  hipLaunchKernelGGL(k_gemm_out, dim3(256, 2), dim3(256), 0, stream,
                     attn_out, Wt_o, bo, g_ws, out);
}